// Round 3
// baseline (868.197 us; speedup 1.0000x reference)
//
#include <hip/hip_runtime.h>
#include <stdint.h>
#include <stddef.h>

// ---------------------------------------------------------------------------
// VQ-VAE quantizer, MI355X.  dist(n,k) = ||x||^2 + ||w_k||^2 - 2 x.w_k.
// f16 GEMM (KD=128) with fragment-linear pre-swizzled A/B -> no LDS, no
// barriers in the K-loop.  Epilogue tracks top-3 (d1,c1,d2,c2,d3) per row.
// Certificate: |dist_err| <= E = 1.5*2^-9*||x||*max||w|| + 2e-4.
//   gap12 > 2E             -> c1 is exact argmin.
//   gap12 <= 2E < gap13    -> exact fp32 compare of c1 vs c2 only.
//   gap13 <= 2E            -> full fp32 rescan (R2-proven kernel).
// ---------------------------------------------------------------------------

#define N_ROWS   16384      // B*H*W = 16*32*32
#define K_CODES  8192
#define C_DIM    128

typedef _Float16 f16x8 __attribute__((ext_vector_type(8)));
typedef float    f32x4 __attribute__((ext_vector_type(4)));

// ---------------- prep: pack encodings -> Ap fragment-linear, xnorm --------
// Ap layout: half Ap[rowtile R=n>>4][kchunk C=c>>5][lane][8]
//   lane = (n&15) + 16*((c&31)>>3), elem j = c&7   (MFMA A-operand order)
__global__ __launch_bounds__(256) void prep_x(const float* __restrict__ enc,
                                              _Float16* __restrict__ Ap,
                                              float* __restrict__ xnorm) {
  __shared__ float t[128][65];
  const int tid = threadIdx.x;
  const int b = blockIdx.x >> 4;
  const int hw0 = (blockIdx.x & 15) << 6;
  #pragma unroll
  for (int i = 0; i < 32; ++i) {
    int idx = i * 256 + tid;
    int c = idx >> 6, hwl = idx & 63;
    t[c][hwl] = enc[((size_t)(b * 128 + c) << 10) + hw0 + hwl];
  }
  __syncthreads();
  const int r = tid >> 2, sub = tid & 3;         // row-in-block, k-chunk
  const int n = (b << 10) + hw0 + r;
  const int R = n >> 4, m = n & 15;
  float s = 0.f;
  #pragma unroll
  for (int q = 0; q < 4; ++q) {
    f16x8 hv;
    #pragma unroll
    for (int e = 0; e < 8; ++e) {
      float v = t[sub * 32 + q * 8 + e][r];
      s += v * v;
      hv[e] = (_Float16)v;
    }
    *(f16x8*)(Ap + ((size_t)(R * 4 + sub) * 64 + (m + 16 * q)) * 8) = hv;
  }
  s += __shfl_xor(s, 1);
  s += __shfl_xor(s, 2);
  if (sub == 0) xnorm[n] = s;
}

// ---------------- prep: pack weight -> Bp fragment-linear, wnorm, wnmax ----
__global__ __launch_bounds__(256) void prep_w(const float* __restrict__ w,
                                              _Float16* __restrict__ Bp,
                                              float* __restrict__ wnorm,
                                              unsigned* __restrict__ wnmax) {
  const int tid = threadIdx.x;
  const int kk = blockIdx.x * 64 + (tid >> 2), sub = tid & 3;
  const int R = kk >> 4, m = kk & 15;
  const float* base = w + (size_t)kk * C_DIM + sub * 32;
  float s = 0.f;
  #pragma unroll
  for (int q = 0; q < 4; ++q) {
    f16x8 hv;
    float4 va = *(const float4*)(base + q * 8);
    float4 vb = *(const float4*)(base + q * 8 + 4);
    float vv[8] = {va.x, va.y, va.z, va.w, vb.x, vb.y, vb.z, vb.w};
    #pragma unroll
    for (int e = 0; e < 8; ++e) { s += vv[e] * vv[e]; hv[e] = (_Float16)vv[e]; }
    *(f16x8*)(Bp + ((size_t)(R * 4 + sub) * 64 + (m + 16 * q)) * 8) = hv;
  }
  s += __shfl_xor(s, 1);
  s += __shfl_xor(s, 2);
  if (sub == 0) {
    wnorm[kk] = s;
    atomicMax(wnmax, __float_as_uint(s));        // s > 0 -> bit-monotone
  }
}

// ---------------- main GEMM + fused per-row top-3 --------------------------
// 128x128 tile, 4 waves 2x2, wave tile 64x64 = 4x4 MFMA f32_16x16x32_f16.
// Fragments loaded straight from global (L1/L2); no LDS, no main-loop barrier.
__global__ __launch_bounds__(256, 4) void gemm_argmin(
    const _Float16* __restrict__ Ap, const _Float16* __restrict__ Bp,
    const float* __restrict__ xnorm, const float* __restrict__ wnorm,
    float* __restrict__ pd1, unsigned* __restrict__ pc1,
    float* __restrict__ pd2, unsigned* __restrict__ pc2,
    float* __restrict__ pd3)
{
  __shared__ float    e_d1[256], e_d2[256], e_d3[256];
  __shared__ unsigned e_c1[256], e_c2[256];
  const int tid = threadIdx.x;
  const int lane = tid & 63, wave = tid >> 6;
  const int wr = wave >> 1, wc = wave & 1;
  const int m = lane & 15, q = lane >> 4;
  const int row0 = blockIdx.y * 128, col0 = blockIdx.x * 128;
  const int Tr0 = blockIdx.y * 8 + wr * 4;       // A row-tiles (16 rows each)
  const int Tc0 = blockIdx.x * 8 + wc * 4;       // B code-tiles

  f32x4 acc[4][4];
  #pragma unroll
  for (int i = 0; i < 4; ++i)
    #pragma unroll
    for (int j = 0; j < 4; ++j) acc[i][j] = (f32x4){0.f, 0.f, 0.f, 0.f};

  #pragma unroll
  for (int kc = 0; kc < 4; ++kc) {
    f16x8 a[4], b[4];
    #pragma unroll
    for (int ti = 0; ti < 4; ++ti)
      a[ti] = *(const f16x8*)(Ap + (((size_t)(Tr0 + ti) * 4 + kc) << 9) + (lane << 3));
    #pragma unroll
    for (int tj = 0; tj < 4; ++tj)
      b[tj] = *(const f16x8*)(Bp + (((size_t)(Tc0 + tj) * 4 + kc) << 9) + (lane << 3));
    #pragma unroll
    for (int ti = 0; ti < 4; ++ti)
      #pragma unroll
      for (int tj = 0; tj < 4; ++tj)
        acc[ti][tj] = __builtin_amdgcn_mfma_f32_16x16x32_f16(
            a[ti], b[tj], acc[ti][tj], 0, 0, 0);
  }

  // ---- epilogue: dist + per-row top3; C/D layout col=lane&15, row=4q+r ----
  float wn[4];
  #pragma unroll
  for (int tj = 0; tj < 4; ++tj) wn[tj] = wnorm[col0 + wc * 64 + tj * 16 + m];

  #pragma unroll
  for (int ti = 0; ti < 4; ++ti) {
    #pragma unroll
    for (int r_ = 0; r_ < 4; ++r_) {
      int row_l = wr * 64 + ti * 16 + 4 * q + r_;
      float xn = xnorm[row0 + row_l];
      float d1 = __builtin_inff(), d2 = __builtin_inff(), d3 = __builtin_inff();
      unsigned c1 = 0, c2 = 0;
      #pragma unroll
      for (int tj = 0; tj < 4; ++tj) {           // ascending col; tie -> lower
        float dd = (xn + wn[tj]) - 2.0f * acc[ti][tj][r_];
        unsigned cc = (unsigned)(col0 + wc * 64 + tj * 16 + m);
        if (dd < d1)      { d3 = d2; d2 = d1; c2 = c1; d1 = dd; c1 = cc; }
        else if (dd < d2) { d3 = d2; d2 = dd; c2 = cc; }
        else              { d3 = fminf(d3, dd); }
      }
      #pragma unroll
      for (int s = 1; s <= 8; s <<= 1) {         // 16-lane butterfly over m
        float    od1 = __shfl_xor(d1, s), od2 = __shfl_xor(d2, s), od3 = __shfl_xor(d3, s);
        unsigned oc1 = (unsigned)__shfl_xor((int)c1, s);
        unsigned oc2 = (unsigned)__shfl_xor((int)c2, s);
        // merge two sorted triples; index-compare keeps first-min tie rule
        if (od1 < d1 || (od1 == d1 && oc1 < c1)) {
          float td = d1; unsigned tc = c1; d1 = od1; c1 = oc1; od1 = td; oc1 = tc;
          td = d2; tc = c2; d2 = od2; c2 = oc2; od2 = td; oc2 = tc;
          float t3 = d3; d3 = od3; od3 = t3;
        }
        if (od1 < d2 || (od1 == d2 && oc1 < c2)) {
          d3 = fminf(d2, od2); d2 = od1; c2 = oc1;
        } else {
          d3 = fminf(d3, od1);
        }
      }
      if (m == 0) {
        int ei = wc * 128 + row_l;
        e_d1[ei] = d1; e_c1[ei] = c1; e_d2[ei] = d2; e_c2[ei] = c2; e_d3[ei] = d3;
      }
    }
  }
  __syncthreads();
  if (tid < 128) {                               // merge the 2 col-halves
    float d1 = e_d1[tid], d2 = e_d2[tid], d3 = e_d3[tid];
    unsigned c1 = e_c1[tid], c2 = e_c2[tid];
    float od1 = e_d1[128 + tid], od2 = e_d2[128 + tid], od3 = e_d3[128 + tid];
    unsigned oc1 = e_c1[128 + tid], oc2 = e_c2[128 + tid];
    if (od1 < d1 || (od1 == d1 && oc1 < c1)) {
      float td = d1; unsigned tc = c1; d1 = od1; c1 = oc1; od1 = td; oc1 = tc;
      td = d2; tc = c2; d2 = od2; c2 = oc2; od2 = td; oc2 = tc;
      float t3 = d3; d3 = od3; od3 = t3;
    }
    if (od1 < d2 || (od1 == d2 && oc1 < c2)) {
      d3 = fminf(d2, od2); d2 = od1; c2 = oc1;
    } else {
      d3 = fminf(d3, od1);
    }
    size_t pi = (size_t)blockIdx.x * N_ROWS + (size_t)(row0 + tid);
    pd1[pi] = d1; pc1[pi] = c1; pd2[pi] = d2; pc2[pi] = c2; pd3[pi] = d3;
  }
}

// ---------------- merge partials across 64 colblocks + classify ------------
__global__ void merge_partials(const float* __restrict__ pd1,
                               const unsigned* __restrict__ pc1,
                               const float* __restrict__ pd2,
                               const unsigned* __restrict__ pc2,
                               const float* __restrict__ pd3,
                               const float* __restrict__ xnorm,
                               const unsigned* __restrict__ wnmax,
                               int* __restrict__ ids,
                               unsigned long long* __restrict__ pairl,
                               unsigned* __restrict__ pcount,
                               int* __restrict__ fulll,
                               unsigned* __restrict__ fcount,
                               float* __restrict__ out_ids) {
  int row = blockIdx.x * 256 + threadIdx.x;
  float d1 = pd1[row], d2 = pd2[row], d3 = pd3[row];
  unsigned c1 = pc1[row], c2 = pc2[row];
  for (int cb = 1; cb < 64; ++cb) {
    size_t i = (size_t)cb * N_ROWS + row;
    float od1 = pd1[i], od2 = pd2[i], od3 = pd3[i];
    unsigned oc1 = pc1[i], oc2 = pc2[i];
    if (od1 < d1 || (od1 == d1 && oc1 < c1)) {
      float td = d1; unsigned tc = c1; d1 = od1; c1 = oc1; od1 = td; oc1 = tc;
      td = d2; tc = c2; d2 = od2; c2 = oc2; od2 = td; oc2 = tc;
      float t3 = d3; d3 = od3; od3 = t3;
    }
    if (od1 < d2 || (od1 == d2 && oc1 < c2)) {
      d3 = fminf(d2, od2); d2 = od1; c2 = oc1;
    } else {
      d3 = fminf(d3, od1);
    }
  }
  ids[row] = (int)c1;
  out_ids[row] = (float)c1;
  // rigorous error window: E = 1.5*2^-9*||x||*max||w|| + 2e-4
  float wm = __uint_as_float(*wnmax);
  float twoE = 2.0f * (0.0029297f * sqrtf(xnorm[row] * wm) + 2e-4f);
  if (d3 - d1 <= twoE) {
    unsigned fi = atomicAdd(fcount, 1u);
    fulll[fi] = row;
  } else if (d2 - d1 <= twoE) {
    unsigned pi = atomicAdd(pcount, 1u);
    pairl[pi] = (unsigned long long)row |
                ((unsigned long long)c1 << 16) |
                ((unsigned long long)c2 << 32);
  }
}

// ---------------- exact fp32 c1-vs-c2 compare (same fmaf order as R2) ------
__global__ void refine_pairs(const float* __restrict__ enc,
                             const float* __restrict__ w,
                             const float* __restrict__ wnorm,
                             const unsigned long long* __restrict__ pairl,
                             const unsigned* __restrict__ pcount,
                             int* __restrict__ ids, float* __restrict__ out_ids) {
  const unsigned cnt = *pcount;
  for (unsigned i = blockIdx.x * blockDim.x + threadIdx.x; i < cnt;
       i += gridDim.x * blockDim.x) {
    unsigned long long u = pairl[i];
    int row = (int)(u & 0xffffu);
    int c1 = (int)((u >> 16) & 0xffffu), c2 = (int)((u >> 32) & 0xffffu);
    int b = row >> 10, hw = row & 1023;
    const float* xb = enc + ((size_t)b << 17) + hw;
    const float* w1 = w + (size_t)c1 * C_DIM;
    const float* w2 = w + (size_t)c2 * C_DIM;
    float xn = 0.f, s1 = 0.f, s2 = 0.f;
    for (int c = 0; c < C_DIM; ++c) {
      float x = xb[(size_t)c << 10];
      xn += x * x;
      s1 = fmaf(x, w1[c], s1);
      s2 = fmaf(x, w2[c], s2);
    }
    float d1 = (xn + wnorm[c1]) - 2.0f * s1;
    float d2 = (xn + wnorm[c2]) - 2.0f * s2;
    if (d2 < d1 || (d2 == d1 && c2 < c1)) { ids[row] = c2; out_ids[row] = (float)c2; }
  }
}

// ---------------- exact fp32 full rescan (R2-proven structure) -------------
__global__ void refine_full(const float* __restrict__ enc,
                            const float* __restrict__ w,
                            const float* __restrict__ wnorm,
                            const int* __restrict__ fulll,
                            const unsigned* __restrict__ fcount,
                            int* __restrict__ ids, float* __restrict__ out_ids) {
  __shared__ float xrow[C_DIM];
  __shared__ unsigned long long red[256];
  const int tid = threadIdx.x;
  const unsigned cnt = *fcount;
  for (unsigned wi = blockIdx.x; wi < cnt; wi += gridDim.x) {
    int row = fulll[wi];
    int b = row >> 10, hw = row & 1023;
    if (tid < C_DIM) xrow[tid] = enc[((size_t)(b * 128 + tid)) * 1024 + hw];
    __syncthreads();
    float xn = 0.f;
    for (int c = 0; c < C_DIM; ++c) xn += xrow[c] * xrow[c];
    unsigned long long best = ~0ull;
    for (int k = tid; k < K_CODES; k += 256) {
      const float4* wk = (const float4*)(w + (size_t)k * C_DIM);
      float S = 0.f;
      #pragma unroll
      for (int c4 = 0; c4 < 32; ++c4) {
        float4 v = wk[c4];
        S = fmaf(xrow[c4 * 4 + 0], v.x, S);
        S = fmaf(xrow[c4 * 4 + 1], v.y, S);
        S = fmaf(xrow[c4 * 4 + 2], v.z, S);
        S = fmaf(xrow[c4 * 4 + 3], v.w, S);
      }
      float d = (xn + wnorm[k]) - 2.0f * S;
      unsigned long long key =
          ((unsigned long long)__float_as_uint(d) << 32) | (unsigned)k;
      best = best < key ? best : key;            // d>0 -> bits monotone; tie->low k
    }
    red[tid] = best;
    __syncthreads();
    for (int s = 128; s > 0; s >>= 1) {
      if (tid < s) red[tid] = red[tid] < red[tid + s] ? red[tid] : red[tid + s];
      __syncthreads();
    }
    if (tid == 0) {
      int k = (int)(red[0] & 0xffffffffu);
      ids[row] = k;
      out_ids[row] = (float)k;
    }
    __syncthreads();
  }
}

// ---------------- scatter stats --------------------------------------------
__global__ void scatter_counts(const int* __restrict__ ids, float* counts) {
  int n = blockIdx.x * 256 + threadIdx.x;
  unsafeAtomicAdd(&counts[ids[n]], 1.0f);
}
__global__ void scatter_sums(const float* __restrict__ enc,
                             const int* __restrict__ ids, float* sums) {
  int e = blockIdx.x * 256 + threadIdx.x;        // linear over enc [B,C,H,W]
  int c = (e >> 10) & 127;
  int b = e >> 17;
  int n = (b << 10) | (e & 1023);
  unsafeAtomicAdd(&sums[(size_t)ids[n] * C_DIM + c], enc[e]);
}

// ---------------- finalize: EMA weight + straight-through q ----------------
__global__ void finalize_w(const float* __restrict__ w,
                           const float* __restrict__ sums,
                           const float* __restrict__ counts,
                           float* __restrict__ outw) {
  int i = blockIdx.x * 256 + threadIdx.x;
  int k = i >> 7;
  const float omd = (float)(1.0 - 0.99);
  float mean = sums[i] / (counts[k] + 1e-12f);
  outw[i] = 0.99f * w[i] + omd * mean;
}
__global__ void write_q(const float* __restrict__ enc,
                        const float* __restrict__ w,
                        const int* __restrict__ ids, float* __restrict__ outq) {
  int e = blockIdx.x * 256 + threadIdx.x;
  int c = (e >> 10) & 127;
  int b = e >> 17;
  int n = (b << 10) | (e & 1023);
  float x = enc[e];
  float wq = w[(size_t)ids[n] * C_DIM + c];
  outq[e] = x + (wq - x);
}

// ---------------------------------------------------------------------------
extern "C" void kernel_launch(void* const* d_in, const int* in_sizes, int n_in,
                              void* d_out, int out_size, void* d_ws, size_t ws_size,
                              hipStream_t stream) {
  const float* enc = (const float*)d_in[0];      // [16,128,32,32]
  const float* w   = (const float*)d_in[1];      // [8192,128]
  float* out = (float*)d_out;
  float* out_ids = out;                          // 16384 (ids as float)
  float* out_q   = out + N_ROWS;                 // 2097152
  float* out_w   = out + N_ROWS + N_ROWS * C_DIM;// 1048576

  char* ws = (char*)d_ws;
  _Float16* Ap  = (_Float16*)(ws);                         // 4194304 B
  _Float16* Bp  = (_Float16*)(ws + 4194304);               // 2097152 B -> 6291456
  float* xnorm  = (float*)(ws + 6291456);                  //   65536 -> 6356992
  float* wnorm  = (float*)(ws + 6356992);                  //   32768 -> 6389760
  float* pd1    = (float*)(ws + 6389760);                  // 4194304 -> 10584064
  float* pd2    = (float*)(ws + 10584064);                 // 4194304 -> 14778368
  float* pd3    = (float*)(ws + 14778368);                 // 4194304 -> 18972672
  unsigned* pc1 = (unsigned*)(ws + 18972672);              // 4194304 -> 23166976
  unsigned* pc2 = (unsigned*)(ws + 23166976);              // 4194304 -> 27361280
  int* ids      = (int*)(ws + 27361280);                   //   65536 -> 27426816
  unsigned long long* pairl = (unsigned long long*)(ws + 27426816); // 131072 -> 27557888
  int* fulll    = (int*)(ws + 27557888);                   //   65536 -> 27623424
  unsigned* wnmax  = (unsigned*)(ws + 27623424);           // ctrl block 16 B
  unsigned* pcount = (unsigned*)(ws + 27623428);
  unsigned* fcount = (unsigned*)(ws + 27623432);
  float* counts = (float*)(ws + 27623440);                 //   32768 -> 27656208
  float* sums   = (float*)(ws + 27656208);                 // 4194304 -> 31850512
  (void)in_sizes; (void)n_in; (void)out_size; (void)ws_size;

  // zero ctrl block + counts + sums (contiguous from 27623424)
  hipMemsetAsync(ws + 27623424, 0, 16 + 32768 + 4194304, stream);

  prep_x<<<256, 256, 0, stream>>>(enc, Ap, xnorm);
  prep_w<<<K_CODES / 64, 256, 0, stream>>>(w, Bp, wnorm, wnmax);
  gemm_argmin<<<dim3(K_CODES / 128, N_ROWS / 128), 256, 0, stream>>>(
      Ap, Bp, xnorm, wnorm, pd1, pc1, pd2, pc2, pd3);
  merge_partials<<<N_ROWS / 256, 256, 0, stream>>>(
      pd1, pc1, pd2, pc2, pd3, xnorm, wnmax, ids, pairl, pcount, fulll, fcount,
      out_ids);
  refine_pairs<<<64, 256, 0, stream>>>(enc, w, wnorm, pairl, pcount, ids, out_ids);
  refine_full<<<256, 256, 0, stream>>>(enc, w, wnorm, fulll, fcount, ids, out_ids);
  scatter_counts<<<N_ROWS / 256, 256, 0, stream>>>(ids, counts);
  scatter_sums<<<(N_ROWS * C_DIM) / 256, 256, 0, stream>>>(enc, ids, sums);
  finalize_w<<<(K_CODES * C_DIM) / 256, 256, 0, stream>>>(w, sums, counts, out_w);
  write_q<<<(N_ROWS * C_DIM) / 256, 256, 0, stream>>>(enc, w, ids, out_q);
}

// Round 4
// 587.449 us; speedup vs baseline: 1.4779x; 1.4779x over previous
//
#include <hip/hip_runtime.h>
#include <stdint.h>
#include <stddef.h>

// ---------------------------------------------------------------------------
// VQ-VAE quantizer, MI355X.  dist(n,k) = ||x||^2 + ||w_k||^2 - 2 x.w_k.
// f16 GEMM (KD=128), fragment-linear A/B, no LDS/barriers in K-loop.
// Refine architecture (R4): per-row threshold T = d1~ + 2E.
//   - every colblock with top1~ <= T contributes its top-1 code as candidate
//   - if any colblock's top2~ <= T -> that block may hide the true argmin
//     behind its top-1 -> exact full rescan for the row (R2-proven kernel)
//   - candidates resolved by exact fp32 distance + u64 atomicMin key
// Proof: for any exact argmin k* in block b: pd1[b] <= d~(k*) <= d(k*)+E
//   <= d(c1g)+E <= d1~+2E = T.  If pd2[b] > T >= d~(k*) then k* is block
//   b's strict top-1 -> collected.  Else full-flag.  Ties -> lowest index
//   via key packing.  E = 1.5*2^-9*sqrt(xnorm*max wnorm) + 2e-4 (f16 RNE
//   conversion 2^-11/input + fp32 accum slack, 1.5x safety).
// ---------------------------------------------------------------------------

#define N_ROWS   16384      // B*H*W = 16*32*32
#define K_CODES  8192
#define C_DIM    128

typedef _Float16 f16x8 __attribute__((ext_vector_type(8)));
typedef float    f32x4 __attribute__((ext_vector_type(4)));

// ---------------- prep: pack encodings -> Ap fragment-linear, xnorm --------
// Ap layout: half Ap[rowtile R=n>>4][kchunk C=c>>5][lane][8]
//   lane = (n&15) + 16*((c&31)>>3), elem j = c&7   (MFMA A-operand order)
__global__ __launch_bounds__(256) void prep_x(const float* __restrict__ enc,
                                              _Float16* __restrict__ Ap,
                                              float* __restrict__ xnorm) {
  __shared__ float t[128][65];
  const int tid = threadIdx.x;
  const int b = blockIdx.x >> 4;
  const int hw0 = (blockIdx.x & 15) << 6;
  #pragma unroll
  for (int i = 0; i < 32; ++i) {
    int idx = i * 256 + tid;
    int c = idx >> 6, hwl = idx & 63;
    t[c][hwl] = enc[((size_t)(b * 128 + c) << 10) + hw0 + hwl];
  }
  __syncthreads();
  const int r = tid >> 2, sub = tid & 3;         // row-in-block, k-chunk
  const int n = (b << 10) + hw0 + r;
  const int R = n >> 4, m = n & 15;
  float s = 0.f;
  #pragma unroll
  for (int q = 0; q < 4; ++q) {
    f16x8 hv;
    #pragma unroll
    for (int e = 0; e < 8; ++e) {
      float v = t[sub * 32 + q * 8 + e][r];
      s += v * v;
      hv[e] = (_Float16)v;
    }
    *(f16x8*)(Ap + ((size_t)(R * 4 + sub) * 64 + (m + 16 * q)) * 8) = hv;
  }
  s += __shfl_xor(s, 1);
  s += __shfl_xor(s, 2);
  if (sub == 0) xnorm[n] = s;
}

// ---------------- prep: pack weight -> Bp fragment-linear, wnorm, wnmax ----
__global__ __launch_bounds__(256) void prep_w(const float* __restrict__ w,
                                              _Float16* __restrict__ Bp,
                                              float* __restrict__ wnorm,
                                              unsigned* __restrict__ wnmax) {
  const int tid = threadIdx.x;
  const int kk = blockIdx.x * 64 + (tid >> 2), sub = tid & 3;
  const int R = kk >> 4, m = kk & 15;
  const float* base = w + (size_t)kk * C_DIM + sub * 32;
  float s = 0.f;
  #pragma unroll
  for (int q = 0; q < 4; ++q) {
    f16x8 hv;
    float4 va = *(const float4*)(base + q * 8);
    float4 vb = *(const float4*)(base + q * 8 + 4);
    float vv[8] = {va.x, va.y, va.z, va.w, vb.x, vb.y, vb.z, vb.w};
    #pragma unroll
    for (int e = 0; e < 8; ++e) { s += vv[e] * vv[e]; hv[e] = (_Float16)vv[e]; }
    *(f16x8*)(Bp + ((size_t)(R * 4 + sub) * 64 + (m + 16 * q)) * 8) = hv;
  }
  s += __shfl_xor(s, 1);
  s += __shfl_xor(s, 2);
  if (sub == 0) {
    wnorm[kk] = s;
    atomicMax(wnmax, __float_as_uint(s));        // s > 0 -> bit-monotone
  }
}

// ---------------- main GEMM + fused per-(row,colblock) top-2 ---------------
// 128x128 tile, 4 waves 2x2, wave tile 64x64 = 4x4 MFMA f32_16x16x32_f16.
// Fragments loaded straight from global (L1/L2); no LDS, no main-loop barrier.
__global__ __launch_bounds__(256, 4) void gemm_argmin(
    const _Float16* __restrict__ Ap, const _Float16* __restrict__ Bp,
    const float* __restrict__ xnorm, const float* __restrict__ wnorm,
    float* __restrict__ pd1, unsigned* __restrict__ pc1,
    float* __restrict__ pd2)
{
  __shared__ float    e_d1[256], e_d2[256];
  __shared__ unsigned e_c1[256];
  const int tid = threadIdx.x;
  const int lane = tid & 63, wave = tid >> 6;
  const int wr = wave >> 1, wc = wave & 1;
  const int m = lane & 15, q = lane >> 4;
  const int row0 = blockIdx.y * 128, col0 = blockIdx.x * 128;
  const int Tr0 = blockIdx.y * 8 + wr * 4;       // A row-tiles (16 rows each)
  const int Tc0 = blockIdx.x * 8 + wc * 4;       // B code-tiles

  f32x4 acc[4][4];
  #pragma unroll
  for (int i = 0; i < 4; ++i)
    #pragma unroll
    for (int j = 0; j < 4; ++j) acc[i][j] = (f32x4){0.f, 0.f, 0.f, 0.f};

  #pragma unroll
  for (int kc = 0; kc < 4; ++kc) {
    f16x8 a[4], b[4];
    #pragma unroll
    for (int ti = 0; ti < 4; ++ti)
      a[ti] = *(const f16x8*)(Ap + (((size_t)(Tr0 + ti) * 4 + kc) << 9) + (lane << 3));
    #pragma unroll
    for (int tj = 0; tj < 4; ++tj)
      b[tj] = *(const f16x8*)(Bp + (((size_t)(Tc0 + tj) * 4 + kc) << 9) + (lane << 3));
    #pragma unroll
    for (int ti = 0; ti < 4; ++ti)
      #pragma unroll
      for (int tj = 0; tj < 4; ++tj)
        acc[ti][tj] = __builtin_amdgcn_mfma_f32_16x16x32_f16(
            a[ti], b[tj], acc[ti][tj], 0, 0, 0);
  }

  // ---- epilogue: dist + per-row top2; C/D layout col=lane&15, row=4q+r ----
  float wn[4];
  #pragma unroll
  for (int tj = 0; tj < 4; ++tj) wn[tj] = wnorm[col0 + wc * 64 + tj * 16 + m];

  #pragma unroll
  for (int ti = 0; ti < 4; ++ti) {
    #pragma unroll
    for (int r_ = 0; r_ < 4; ++r_) {
      int row_l = wr * 64 + ti * 16 + 4 * q + r_;
      float xn = xnorm[row0 + row_l];
      float d1 = __builtin_inff(), d2 = __builtin_inff();
      unsigned c1 = 0;
      #pragma unroll
      for (int tj = 0; tj < 4; ++tj) {           // ascending col; tie -> lower
        float dd = (xn + wn[tj]) - 2.0f * acc[ti][tj][r_];
        unsigned cc = (unsigned)(col0 + wc * 64 + tj * 16 + m);
        if (dd < d1) { d2 = d1; d1 = dd; c1 = cc; }
        else         { d2 = fminf(d2, dd); }
      }
      #pragma unroll
      for (int s = 1; s <= 8; s <<= 1) {         // 16-lane butterfly over m
        float    od1 = __shfl_xor(d1, s), od2 = __shfl_xor(d2, s);
        unsigned oc1 = (unsigned)__shfl_xor((int)c1, s);
        float nd2 = fminf(fminf(d2, od2), fmaxf(d1, od1));
        if (od1 < d1 || (od1 == d1 && oc1 < c1)) { d1 = od1; c1 = oc1; }
        d2 = nd2;
      }
      if (m == 0) {
        int ei = wc * 128 + row_l;
        e_d1[ei] = d1; e_c1[ei] = c1; e_d2[ei] = d2;
      }
    }
  }
  __syncthreads();
  if (tid < 128) {                               // merge the 2 col-halves
    float d1 = e_d1[tid], d2 = e_d2[tid];
    unsigned c1 = e_c1[tid];
    float od1 = e_d1[128 + tid], od2 = e_d2[128 + tid];
    unsigned oc1 = e_c1[128 + tid];
    float nd2 = fminf(fminf(d2, od2), fmaxf(d1, od1));
    if (od1 < d1 || (od1 == d1 && oc1 < c1)) { d1 = od1; c1 = oc1; }
    d2 = nd2;
    size_t pi = (size_t)blockIdx.x * N_ROWS + (size_t)(row0 + tid);
    pd1[pi] = d1; pc1[pi] = c1; pd2[pi] = d2;
  }
}

// ---------------- classify: threshold-collect over 64 colblocks ------------
__global__ void merge_classify(const float* __restrict__ pd1,
                               const unsigned* __restrict__ pc1,
                               const float* __restrict__ pd2,
                               const float* __restrict__ xnorm,
                               const unsigned* __restrict__ wnmax,
                               int* __restrict__ ids,
                               unsigned* __restrict__ items,
                               unsigned* __restrict__ icount,
                               int* __restrict__ fulll,
                               unsigned* __restrict__ fcount,
                               float* __restrict__ out_ids) {
  int row = blockIdx.x * 256 + threadIdx.x;
  // pass 1: global top-1 (ascending colblock -> first-min tie rule)
  float d1 = __builtin_inff();
  unsigned c1 = 0;
  for (int cb = 0; cb < 64; ++cb) {
    size_t i = (size_t)cb * N_ROWS + row;
    float od = pd1[i];
    if (od < d1) { d1 = od; c1 = pc1[i]; }       // blocks ascending in col
  }
  float wm = __uint_as_float(*wnmax);
  float twoE = 2.0f * (0.0029297f * sqrtf(xnorm[row] * wm) + 2e-4f);
  float T = d1 + twoE;
  // pass 2: collect candidate codes / full-rescan flag
  bool full = false;
  int nc = 0;
  unsigned cands[6];
  for (int cb = 0; cb < 64; ++cb) {
    size_t i = (size_t)cb * N_ROWS + row;
    if (pd2[i] <= T) { full = true; }
    else if (pd1[i] <= T) {
      if (nc < 6) cands[nc++] = pc1[i];
      else full = true;
    }
  }
  ids[row] = (int)c1;                            // provisional (exact if nc==1 && !full)
  out_ids[row] = (float)c1;
  if (full) {
    unsigned fi = atomicAdd(fcount, 1u);
    fulll[fi] = row;
  } else if (nc >= 2) {
    unsigned base = atomicAdd(icount, (unsigned)nc);
    for (int i = 0; i < nc; ++i)
      items[base + i] = ((unsigned)row << 13) | cands[i];
  }
}

// ---------------- exact fp32 per-candidate compare (atomicMin key) ---------
__global__ void refine_items(const float* __restrict__ enc,
                             const float* __restrict__ w,
                             const float* __restrict__ wnorm,
                             const unsigned* __restrict__ items,
                             const unsigned* __restrict__ icount,
                             unsigned long long* __restrict__ keys) {
  const unsigned cnt = *icount;
  for (unsigned i = blockIdx.x * blockDim.x + threadIdx.x; i < cnt;
       i += gridDim.x * blockDim.x) {
    unsigned it = items[i];
    int row = (int)(it >> 13), c = (int)(it & 8191u);
    int b = row >> 10, hw = row & 1023;
    const float* xb = enc + ((size_t)b << 17) + hw;
    const float* wk = w + (size_t)c * C_DIM;
    float xn = 0.f, s = 0.f;
    for (int cc = 0; cc < C_DIM; ++cc) {
      float x = xb[(size_t)cc << 10];
      xn += x * x;
      s = fmaf(x, wk[cc], s);
    }
    float d = (xn + wnorm[c]) - 2.0f * s;
    unsigned sb = __float_as_uint(d);
    sb = (sb >> 31) ? ~sb : (sb | 0x80000000u);  // sortable float bits
    unsigned long long key = ((unsigned long long)sb << 32) | (unsigned)c;
    atomicMin(&keys[row], key);                  // tie -> lowest code
  }
}

// ---------------- resolve candidate rows from keys -------------------------
__global__ void resolve_keys(const unsigned long long* __restrict__ keys,
                             int* __restrict__ ids, float* __restrict__ out_ids) {
  int row = blockIdx.x * 256 + threadIdx.x;
  unsigned long long k = keys[row];
  if (k != ~0ull) {
    int c = (int)(unsigned)(k & 0xffffffffu);
    ids[row] = c;
    out_ids[row] = (float)c;
  }
}

// ---------------- exact fp32 full rescan (R2-proven structure) -------------
__global__ void refine_full(const float* __restrict__ enc,
                            const float* __restrict__ w,
                            const float* __restrict__ wnorm,
                            const int* __restrict__ fulll,
                            const unsigned* __restrict__ fcount,
                            int* __restrict__ ids, float* __restrict__ out_ids) {
  __shared__ float xrow[C_DIM];
  __shared__ unsigned long long red[256];
  const int tid = threadIdx.x;
  const unsigned cnt = *fcount;
  for (unsigned wi = blockIdx.x; wi < cnt; wi += gridDim.x) {
    int row = fulll[wi];
    int b = row >> 10, hw = row & 1023;
    if (tid < C_DIM) xrow[tid] = enc[((size_t)(b * 128 + tid)) * 1024 + hw];
    __syncthreads();
    float xn = 0.f;
    for (int c = 0; c < C_DIM; ++c) xn += xrow[c] * xrow[c];
    unsigned long long best = ~0ull;
    for (int k = tid; k < K_CODES; k += 256) {
      const float4* wk = (const float4*)(w + (size_t)k * C_DIM);
      float S = 0.f;
      #pragma unroll
      for (int c4 = 0; c4 < 32; ++c4) {
        float4 v = wk[c4];
        S = fmaf(xrow[c4 * 4 + 0], v.x, S);
        S = fmaf(xrow[c4 * 4 + 1], v.y, S);
        S = fmaf(xrow[c4 * 4 + 2], v.z, S);
        S = fmaf(xrow[c4 * 4 + 3], v.w, S);
      }
      float d = (xn + wnorm[k]) - 2.0f * S;
      unsigned long long key =
          ((unsigned long long)__float_as_uint(d) << 32) | (unsigned)k;
      best = best < key ? best : key;            // d>0 -> bits monotone; tie->low k
    }
    red[tid] = best;
    __syncthreads();
    for (int s = 128; s > 0; s >>= 1) {
      if (tid < s) red[tid] = red[tid] < red[tid + s] ? red[tid] : red[tid + s];
      __syncthreads();
    }
    if (tid == 0) {
      int k = (int)(red[0] & 0xffffffffu);
      ids[row] = k;
      out_ids[row] = (float)k;
    }
    __syncthreads();
  }
}

// ---------------- scatter stats --------------------------------------------
__global__ void scatter_counts(const int* __restrict__ ids, float* counts) {
  int n = blockIdx.x * 256 + threadIdx.x;
  unsafeAtomicAdd(&counts[ids[n]], 1.0f);
}
__global__ void scatter_sums(const float* __restrict__ enc,
                             const int* __restrict__ ids, float* sums) {
  int e = blockIdx.x * 256 + threadIdx.x;        // linear over enc [B,C,H,W]
  int c = (e >> 10) & 127;
  int b = e >> 17;
  int n = (b << 10) | (e & 1023);
  unsafeAtomicAdd(&sums[(size_t)ids[n] * C_DIM + c], enc[e]);
}

// ---------------- finalize: EMA weight + straight-through q ----------------
__global__ void finalize_w(const float* __restrict__ w,
                           const float* __restrict__ sums,
                           const float* __restrict__ counts,
                           float* __restrict__ outw) {
  int i = blockIdx.x * 256 + threadIdx.x;
  int k = i >> 7;
  const float omd = (float)(1.0 - 0.99);
  float mean = sums[i] / (counts[k] + 1e-12f);
  outw[i] = 0.99f * w[i] + omd * mean;
}
__global__ void write_q(const float* __restrict__ enc,
                        const float* __restrict__ w,
                        const int* __restrict__ ids, float* __restrict__ outq) {
  int e = blockIdx.x * 256 + threadIdx.x;
  int c = (e >> 10) & 127;
  int b = e >> 17;
  int n = (b << 10) | (e & 1023);
  float x = enc[e];
  float wq = w[(size_t)ids[n] * C_DIM + c];
  outq[e] = x + (wq - x);
}

// ---------------------------------------------------------------------------
extern "C" void kernel_launch(void* const* d_in, const int* in_sizes, int n_in,
                              void* d_out, int out_size, void* d_ws, size_t ws_size,
                              hipStream_t stream) {
  const float* enc = (const float*)d_in[0];      // [16,128,32,32]
  const float* w   = (const float*)d_in[1];      // [8192,128]
  float* out = (float*)d_out;
  float* out_ids = out;                          // 16384 (ids as float)
  float* out_q   = out + N_ROWS;                 // 2097152
  float* out_w   = out + N_ROWS + N_ROWS * C_DIM;// 1048576

  char* ws = (char*)d_ws;
  _Float16* Ap  = (_Float16*)(ws);                         //  0 .. 4194304
  _Float16* Bp  = (_Float16*)(ws + 4194304);               //  .. 6291456
  float* xnorm  = (float*)(ws + 6291456);                  //  .. 6356992
  float* wnorm  = (float*)(ws + 6356992);                  //  .. 6389760
  float* pd1    = (float*)(ws + 6389760);                  //  .. 10584064
  float* pd2    = (float*)(ws + 10584064);                 //  .. 14778368
  unsigned* pc1 = (unsigned*)(ws + 14778368);              //  .. 18972672
  int* ids      = (int*)(ws + 18972672);                   //  .. 19038208
  int* fulll    = (int*)(ws + 19038208);                   //  .. 19103744
  unsigned* items = (unsigned*)(ws + 19103744);            //  .. 20152320
  unsigned* wnmax  = (unsigned*)(ws + 20152320);           // ctrl 16 B
  unsigned* icount = (unsigned*)(ws + 20152324);
  unsigned* fcount = (unsigned*)(ws + 20152328);
  float* counts = (float*)(ws + 20152336);                 //  .. 20185104
  float* sums   = (float*)(ws + 20185104);                 //  .. 24379408
  unsigned long long* keys = (unsigned long long*)(ws + 24379408); // .. 24510480
  (void)in_sizes; (void)n_in; (void)out_size; (void)ws_size;

  // zero ctrl+counts+sums, then 0xFF keys (keys sentinel = ~0ull)
  hipMemsetAsync(ws + 20152320, 0, 16 + 32768 + 4194304, stream);
  hipMemsetAsync(ws + 24379408, 0xFF, N_ROWS * 8, stream);

  prep_x<<<256, 256, 0, stream>>>(enc, Ap, xnorm);
  prep_w<<<K_CODES / 64, 256, 0, stream>>>(w, Bp, wnorm, wnmax);
  gemm_argmin<<<dim3(K_CODES / 128, N_ROWS / 128), 256, 0, stream>>>(
      Ap, Bp, xnorm, wnorm, pd1, pc1, pd2);
  merge_classify<<<N_ROWS / 256, 256, 0, stream>>>(
      pd1, pc1, pd2, xnorm, wnmax, ids, items, icount, fulll, fcount, out_ids);
  refine_items<<<256, 256, 0, stream>>>(enc, w, wnorm, items, icount, keys);
  resolve_keys<<<N_ROWS / 256, 256, 0, stream>>>(keys, ids, out_ids);
  refine_full<<<2048, 256, 0, stream>>>(enc, w, wnorm, fulll, fcount, ids, out_ids);
  scatter_counts<<<N_ROWS / 256, 256, 0, stream>>>(ids, counts);
  scatter_sums<<<(N_ROWS * C_DIM) / 256, 256, 0, stream>>>(enc, ids, sums);
  finalize_w<<<(K_CODES * C_DIM) / 256, 256, 0, stream>>>(w, sums, counts, out_w);
  write_q<<<(N_ROWS * C_DIM) / 256, 256, 0, stream>>>(enc, w, ids, out_q);
}

// Round 5
// 552.572 us; speedup vs baseline: 1.5712x; 1.0631x over previous
//
#include <hip/hip_runtime.h>
#include <stdint.h>
#include <stddef.h>

// ---------------------------------------------------------------------------
// VQ-VAE quantizer, MI355X.  dist(n,k) = ||x||^2 + ||w_k||^2 - 2 x.w_k.
// f16 GEMM (KD=128), fragment-linear A/B, no LDS/barriers in K-loop.
// Refine architecture (R4, proven): per-row threshold T = d1~ + 2E.
//   - every colblock with top1~ <= T contributes its top-1 code as candidate
//   - if any colblock's top2~ <= T -> exact full rescan for the row
//   - candidates resolved by exact fp32 distance + u64 atomicMin key
// R5: refine_full batched 8 rows/block (ILP + codebook amortization);
//     per-(row,code) fp arithmetic order bit-identical to the R4 version.
// ---------------------------------------------------------------------------

#define N_ROWS   16384      // B*H*W = 16*32*32
#define K_CODES  8192
#define C_DIM    128

typedef _Float16 f16x8 __attribute__((ext_vector_type(8)));
typedef float    f32x4 __attribute__((ext_vector_type(4)));

// ---------------- prep: pack encodings -> Ap fragment-linear, xnorm --------
// Ap layout: half Ap[rowtile R=n>>4][kchunk C=c>>5][lane][8]
//   lane = (n&15) + 16*((c&31)>>3), elem j = c&7   (MFMA A-operand order)
__global__ __launch_bounds__(256) void prep_x(const float* __restrict__ enc,
                                              _Float16* __restrict__ Ap,
                                              float* __restrict__ xnorm) {
  __shared__ float t[128][65];
  const int tid = threadIdx.x;
  const int b = blockIdx.x >> 4;
  const int hw0 = (blockIdx.x & 15) << 6;
  #pragma unroll
  for (int i = 0; i < 32; ++i) {
    int idx = i * 256 + tid;
    int c = idx >> 6, hwl = idx & 63;
    t[c][hwl] = enc[((size_t)(b * 128 + c) << 10) + hw0 + hwl];
  }
  __syncthreads();
  const int r = tid >> 2, sub = tid & 3;         // row-in-block, k-chunk
  const int n = (b << 10) + hw0 + r;
  const int R = n >> 4, m = n & 15;
  float s = 0.f;
  #pragma unroll
  for (int q = 0; q < 4; ++q) {
    f16x8 hv;
    #pragma unroll
    for (int e = 0; e < 8; ++e) {
      float v = t[sub * 32 + q * 8 + e][r];
      s += v * v;
      hv[e] = (_Float16)v;
    }
    *(f16x8*)(Ap + ((size_t)(R * 4 + sub) * 64 + (m + 16 * q)) * 8) = hv;
  }
  s += __shfl_xor(s, 1);
  s += __shfl_xor(s, 2);
  if (sub == 0) xnorm[n] = s;
}

// ---------------- prep: pack weight -> Bp fragment-linear, wnorm, wnmax ----
__global__ __launch_bounds__(256) void prep_w(const float* __restrict__ w,
                                              _Float16* __restrict__ Bp,
                                              float* __restrict__ wnorm,
                                              unsigned* __restrict__ wnmax) {
  const int tid = threadIdx.x;
  const int kk = blockIdx.x * 64 + (tid >> 2), sub = tid & 3;
  const int R = kk >> 4, m = kk & 15;
  const float* base = w + (size_t)kk * C_DIM + sub * 32;
  float s = 0.f;
  #pragma unroll
  for (int q = 0; q < 4; ++q) {
    f16x8 hv;
    float4 va = *(const float4*)(base + q * 8);
    float4 vb = *(const float4*)(base + q * 8 + 4);
    float vv[8] = {va.x, va.y, va.z, va.w, vb.x, vb.y, vb.z, vb.w};
    #pragma unroll
    for (int e = 0; e < 8; ++e) { s += vv[e] * vv[e]; hv[e] = (_Float16)vv[e]; }
    *(f16x8*)(Bp + ((size_t)(R * 4 + sub) * 64 + (m + 16 * q)) * 8) = hv;
  }
  s += __shfl_xor(s, 1);
  s += __shfl_xor(s, 2);
  if (sub == 0) {
    wnorm[kk] = s;
    atomicMax(wnmax, __float_as_uint(s));        // s > 0 -> bit-monotone
  }
}

// ---------------- main GEMM + fused per-(row,colblock) top-2 ---------------
// 128x128 tile, 4 waves 2x2, wave tile 64x64 = 4x4 MFMA f32_16x16x32_f16.
// Fragments loaded straight from global (L1/L2); no LDS, no main-loop barrier.
__global__ __launch_bounds__(256, 4) void gemm_argmin(
    const _Float16* __restrict__ Ap, const _Float16* __restrict__ Bp,
    const float* __restrict__ xnorm, const float* __restrict__ wnorm,
    float* __restrict__ pd1, unsigned* __restrict__ pc1,
    float* __restrict__ pd2)
{
  __shared__ float    e_d1[256], e_d2[256];
  __shared__ unsigned e_c1[256];
  const int tid = threadIdx.x;
  const int lane = tid & 63, wave = tid >> 6;
  const int wr = wave >> 1, wc = wave & 1;
  const int m = lane & 15, q = lane >> 4;
  const int row0 = blockIdx.y * 128, col0 = blockIdx.x * 128;
  const int Tr0 = blockIdx.y * 8 + wr * 4;       // A row-tiles (16 rows each)
  const int Tc0 = blockIdx.x * 8 + wc * 4;       // B code-tiles

  f32x4 acc[4][4];
  #pragma unroll
  for (int i = 0; i < 4; ++i)
    #pragma unroll
    for (int j = 0; j < 4; ++j) acc[i][j] = (f32x4){0.f, 0.f, 0.f, 0.f};

  #pragma unroll
  for (int kc = 0; kc < 4; ++kc) {
    f16x8 a[4], b[4];
    #pragma unroll
    for (int ti = 0; ti < 4; ++ti)
      a[ti] = *(const f16x8*)(Ap + (((size_t)(Tr0 + ti) * 4 + kc) << 9) + (lane << 3));
    #pragma unroll
    for (int tj = 0; tj < 4; ++tj)
      b[tj] = *(const f16x8*)(Bp + (((size_t)(Tc0 + tj) * 4 + kc) << 9) + (lane << 3));
    #pragma unroll
    for (int ti = 0; ti < 4; ++ti)
      #pragma unroll
      for (int tj = 0; tj < 4; ++tj)
        acc[ti][tj] = __builtin_amdgcn_mfma_f32_16x16x32_f16(
            a[ti], b[tj], acc[ti][tj], 0, 0, 0);
  }

  // ---- epilogue: dist + per-row top2; C/D layout col=lane&15, row=4q+r ----
  float wn[4];
  #pragma unroll
  for (int tj = 0; tj < 4; ++tj) wn[tj] = wnorm[col0 + wc * 64 + tj * 16 + m];

  #pragma unroll
  for (int ti = 0; ti < 4; ++ti) {
    #pragma unroll
    for (int r_ = 0; r_ < 4; ++r_) {
      int row_l = wr * 64 + ti * 16 + 4 * q + r_;
      float xn = xnorm[row0 + row_l];
      float d1 = __builtin_inff(), d2 = __builtin_inff();
      unsigned c1 = 0;
      #pragma unroll
      for (int tj = 0; tj < 4; ++tj) {           // ascending col; tie -> lower
        float dd = (xn + wn[tj]) - 2.0f * acc[ti][tj][r_];
        unsigned cc = (unsigned)(col0 + wc * 64 + tj * 16 + m);
        if (dd < d1) { d2 = d1; d1 = dd; c1 = cc; }
        else         { d2 = fminf(d2, dd); }
      }
      #pragma unroll
      for (int s = 1; s <= 8; s <<= 1) {         // 16-lane butterfly over m
        float    od1 = __shfl_xor(d1, s), od2 = __shfl_xor(d2, s);
        unsigned oc1 = (unsigned)__shfl_xor((int)c1, s);
        float nd2 = fminf(fminf(d2, od2), fmaxf(d1, od1));
        if (od1 < d1 || (od1 == d1 && oc1 < c1)) { d1 = od1; c1 = oc1; }
        d2 = nd2;
      }
      if (m == 0) {
        int ei = wc * 128 + row_l;
        e_d1[ei] = d1; e_c1[ei] = c1; e_d2[ei] = d2;
      }
    }
  }
  __syncthreads();
  if (tid < 128) {                               // merge the 2 col-halves
    float d1 = e_d1[tid], d2 = e_d2[tid];
    unsigned c1 = e_c1[tid];
    float od1 = e_d1[128 + tid], od2 = e_d2[128 + tid];
    unsigned oc1 = e_c1[128 + tid];
    float nd2 = fminf(fminf(d2, od2), fmaxf(d1, od1));
    if (od1 < d1 || (od1 == d1 && oc1 < c1)) { d1 = od1; c1 = oc1; }
    d2 = nd2;
    size_t pi = (size_t)blockIdx.x * N_ROWS + (size_t)(row0 + tid);
    pd1[pi] = d1; pc1[pi] = c1; pd2[pi] = d2;
  }
}

// ---------------- classify: threshold-collect over 64 colblocks ------------
__global__ void merge_classify(const float* __restrict__ pd1,
                               const unsigned* __restrict__ pc1,
                               const float* __restrict__ pd2,
                               const float* __restrict__ xnorm,
                               const unsigned* __restrict__ wnmax,
                               int* __restrict__ ids,
                               unsigned* __restrict__ items,
                               unsigned* __restrict__ icount,
                               int* __restrict__ fulll,
                               unsigned* __restrict__ fcount,
                               float* __restrict__ out_ids) {
  int row = blockIdx.x * 256 + threadIdx.x;
  // pass 1: global top-1, 4 independent sub-chains (ILP), lex-combine.
  // (d,c) lexicographic min == "first min over ascending colblock" since
  // colblocks are ascending in column index.
  float da = __builtin_inff(), db = __builtin_inff(),
        dc = __builtin_inff(), dd = __builtin_inff();
  unsigned ca = 0, cb_ = 0, cc = 0, cd = 0;
  for (int cb = 0; cb < 64; cb += 4) {
    size_t i0 = (size_t)cb * N_ROWS + row;
    float va = pd1[i0], vb = pd1[i0 + (size_t)N_ROWS],
          vc = pd1[i0 + 2 * (size_t)N_ROWS], vd = pd1[i0 + 3 * (size_t)N_ROWS];
    unsigned ka = pc1[i0], kb = pc1[i0 + (size_t)N_ROWS],
             kc = pc1[i0 + 2 * (size_t)N_ROWS], kd = pc1[i0 + 3 * (size_t)N_ROWS];
    if (va < da || (va == da && ka < ca)) { da = va; ca = ka; }
    if (vb < db || (vb == db && kb < cb_)) { db = vb; cb_ = kb; }
    if (vc < dc || (vc == dc && kc < cc)) { dc = vc; cc = kc; }
    if (vd < dd || (vd == dd && kd < cd)) { dd = vd; cd = kd; }
  }
  float d1 = da; unsigned c1 = ca;
  if (db < d1 || (db == d1 && cb_ < c1)) { d1 = db; c1 = cb_; }
  if (dc < d1 || (dc == d1 && cc < c1)) { d1 = dc; c1 = cc; }
  if (dd < d1 || (dd == d1 && cd < c1)) { d1 = dd; c1 = cd; }

  float wm = __uint_as_float(*wnmax);
  float twoE = 2.0f * (0.0029297f * sqrtf(xnorm[row] * wm) + 2e-4f);
  float T = d1 + twoE;
  // pass 2: collect candidate codes / full-rescan flag (order-independent)
  bool full = false;
  int nc = 0;
  unsigned cands[6];
  #pragma unroll 4
  for (int cb = 0; cb < 64; ++cb) {
    size_t i = (size_t)cb * N_ROWS + row;
    if (pd2[i] <= T) { full = true; }
    else if (pd1[i] <= T) {
      if (nc < 6) cands[nc++] = pc1[i];
      else full = true;
    }
  }
  ids[row] = (int)c1;                            // provisional (exact if nc==1 && !full)
  out_ids[row] = (float)c1;
  if (full) {
    unsigned fi = atomicAdd(fcount, 1u);
    fulll[fi] = row;
  } else if (nc >= 2) {
    unsigned base = atomicAdd(icount, (unsigned)nc);
    for (int i = 0; i < nc; ++i)
      items[base + i] = ((unsigned)row << 13) | cands[i];
  }
}

// ---------------- exact fp32 per-candidate compare (atomicMin key) ---------
__global__ void refine_items(const float* __restrict__ enc,
                             const float* __restrict__ w,
                             const float* __restrict__ wnorm,
                             const unsigned* __restrict__ items,
                             const unsigned* __restrict__ icount,
                             unsigned long long* __restrict__ keys) {
  const unsigned cnt = *icount;
  for (unsigned i = blockIdx.x * blockDim.x + threadIdx.x; i < cnt;
       i += gridDim.x * blockDim.x) {
    unsigned it = items[i];
    int row = (int)(it >> 13), c = (int)(it & 8191u);
    int b = row >> 10, hw = row & 1023;
    const float* xb = enc + ((size_t)b << 17) + hw;
    const float* wk = w + (size_t)c * C_DIM;
    float xn = 0.f, s = 0.f;
    for (int cc = 0; cc < C_DIM; ++cc) {
      float x = xb[(size_t)cc << 10];
      xn += x * x;
      s = fmaf(x, wk[cc], s);
    }
    float d = (xn + wnorm[c]) - 2.0f * s;
    unsigned sb = __float_as_uint(d);
    sb = (sb >> 31) ? ~sb : (sb | 0x80000000u);  // sortable float bits
    unsigned long long key = ((unsigned long long)sb << 32) | (unsigned)c;
    atomicMin(&keys[row], key);                  // tie -> lowest code
  }
}

// ---------------- resolve candidate rows from keys -------------------------
__global__ void resolve_keys(const unsigned long long* __restrict__ keys,
                             int* __restrict__ ids, float* __restrict__ out_ids) {
  int row = blockIdx.x * 256 + threadIdx.x;
  unsigned long long k = keys[row];
  if (k != ~0ull) {
    int c = (int)(unsigned)(k & 0xffffffffu);
    ids[row] = c;
    out_ids[row] = (float)c;
  }
}

// ---------------- exact fp32 full rescan, batched 8 rows/block -------------
// Per-(row,code) arithmetic order is bit-identical to the R4-passing kernel:
// S accumulates channels 0..127 sequentially (float4 elems in order), xn is
// a serial sum, key packing/tie rule unchanged.  8 rows share each code
// fetch (8x less codebook traffic) and give 32 independent fmaf chains.
__global__ __launch_bounds__(256) void refine_full(
    const float* __restrict__ enc, const float* __restrict__ w,
    const float* __restrict__ wnorm,
    const int* __restrict__ fulll, const unsigned* __restrict__ fcount,
    int* __restrict__ ids, float* __restrict__ out_ids) {
  __shared__ __align__(16) float xs[8][128];
  __shared__ float xnL[8];
  __shared__ unsigned long long red[32];
  const int tid = threadIdx.x;
  const int lane = tid & 63, wave = tid >> 6;
  const unsigned cnt = *fcount;
  for (unsigned b0 = blockIdx.x * 8; b0 < cnt; b0 += gridDim.x * 8) {
    const int nr = (int)min(8u, cnt - b0);
    for (int i = tid; i < nr * 128; i += 256) {  // stage xrows
      int r = i >> 7, c = i & 127;
      int row = fulll[b0 + r];
      xs[r][c] = enc[(((size_t)(row >> 10) * 128 + c) << 10) + (row & 1023)];
    }
    __syncthreads();
    if (tid < nr) {                              // serial xn (R4 order)
      float s = 0.f;
      for (int c = 0; c < 128; ++c) s += xs[tid][c] * xs[tid][c];
      xnL[tid] = s;
    }
    __syncthreads();
    unsigned long long best[8];
    #pragma unroll
    for (int r = 0; r < 8; ++r) best[r] = ~0ull;
    for (int kt = 0; kt < 8; ++kt) {             // 8 tiles x 4 codes/thread
      const int k0 = kt * 1024 + tid * 4;
      float S[4][8];
      #pragma unroll
      for (int j = 0; j < 4; ++j)
        #pragma unroll
        for (int r = 0; r < 8; ++r) S[j][r] = 0.f;
      for (int c4 = 0; c4 < 32; ++c4) {
        float4 wv[4];
        #pragma unroll
        for (int j = 0; j < 4; ++j)
          wv[j] = *(const float4*)(w + (size_t)(k0 + j) * C_DIM + c4 * 4);
        #pragma unroll
        for (int r = 0; r < 8; ++r) {
          float4 xv = *(const float4*)(&xs[r][c4 * 4]);
          #pragma unroll
          for (int j = 0; j < 4; ++j) {
            S[j][r] = fmaf(xv.x, wv[j].x, S[j][r]);
            S[j][r] = fmaf(xv.y, wv[j].y, S[j][r]);
            S[j][r] = fmaf(xv.z, wv[j].z, S[j][r]);
            S[j][r] = fmaf(xv.w, wv[j].w, S[j][r]);
          }
        }
      }
      #pragma unroll
      for (int j = 0; j < 4; ++j) {
        float wn = wnorm[k0 + j];
        #pragma unroll
        for (int r = 0; r < 8; ++r) {
          float d = (xnL[r] + wn) - 2.0f * S[j][r];
          unsigned long long key =
              ((unsigned long long)__float_as_uint(d) << 32) | (unsigned)(k0 + j);
          best[r] = best[r] < key ? best[r] : key;   // d>0 -> bits monotone
        }
      }
    }
    #pragma unroll
    for (int r = 0; r < 8; ++r) {                // 64-lane u64 butterfly
      unsigned long long bk = best[r];
      #pragma unroll
      for (int s = 1; s <= 32; s <<= 1) {
        unsigned long long ok = __shfl_xor(bk, s);
        bk = ok < bk ? ok : bk;
      }
      if (lane == 0) red[r * 4 + wave] = bk;
    }
    __syncthreads();
    if (tid < nr) {
      unsigned long long bk = red[tid * 4];
      #pragma unroll
      for (int wv = 1; wv < 4; ++wv) {
        unsigned long long ok = red[tid * 4 + wv];
        bk = ok < bk ? ok : bk;
      }
      int row = fulll[b0 + tid];
      int k = (int)(bk & 0xffffffffu);
      ids[row] = k;
      out_ids[row] = (float)k;
    }
    __syncthreads();                             // xs reused next batch
  }
}

// ---------------- scatter stats --------------------------------------------
__global__ void scatter_counts(const int* __restrict__ ids, float* counts) {
  int n = blockIdx.x * 256 + threadIdx.x;
  unsafeAtomicAdd(&counts[ids[n]], 1.0f);
}
__global__ void scatter_sums(const float* __restrict__ enc,
                             const int* __restrict__ ids, float* sums) {
  int e = blockIdx.x * 256 + threadIdx.x;        // linear over enc [B,C,H,W]
  int c = (e >> 10) & 127;
  int b = e >> 17;
  int n = (b << 10) | (e & 1023);
  unsafeAtomicAdd(&sums[(size_t)ids[n] * C_DIM + c], enc[e]);
}

// ---------------- finalize: EMA weight + straight-through q ----------------
__global__ void finalize_w(const float* __restrict__ w,
                           const float* __restrict__ sums,
                           const float* __restrict__ counts,
                           float* __restrict__ outw) {
  int i = blockIdx.x * 256 + threadIdx.x;
  int k = i >> 7;
  const float omd = (float)(1.0 - 0.99);
  float mean = sums[i] / (counts[k] + 1e-12f);
  outw[i] = 0.99f * w[i] + omd * mean;
}
__global__ void write_q(const float* __restrict__ enc,
                        const float* __restrict__ w,
                        const int* __restrict__ ids, float* __restrict__ outq) {
  int e = blockIdx.x * 256 + threadIdx.x;
  int c = (e >> 10) & 127;
  int b = e >> 17;
  int n = (b << 10) | (e & 1023);
  float x = enc[e];
  float wq = w[(size_t)ids[n] * C_DIM + c];
  outq[e] = x + (wq - x);
}

// ---------------------------------------------------------------------------
extern "C" void kernel_launch(void* const* d_in, const int* in_sizes, int n_in,
                              void* d_out, int out_size, void* d_ws, size_t ws_size,
                              hipStream_t stream) {
  const float* enc = (const float*)d_in[0];      // [16,128,32,32]
  const float* w   = (const float*)d_in[1];      // [8192,128]
  float* out = (float*)d_out;
  float* out_ids = out;                          // 16384 (ids as float)
  float* out_q   = out + N_ROWS;                 // 2097152
  float* out_w   = out + N_ROWS + N_ROWS * C_DIM;// 1048576

  char* ws = (char*)d_ws;
  _Float16* Ap  = (_Float16*)(ws);                         //  0 .. 4194304
  _Float16* Bp  = (_Float16*)(ws + 4194304);               //  .. 6291456
  float* xnorm  = (float*)(ws + 6291456);                  //  .. 6356992
  float* wnorm  = (float*)(ws + 6356992);                  //  .. 6389760
  float* pd1    = (float*)(ws + 6389760);                  //  .. 10584064
  float* pd2    = (float*)(ws + 10584064);                 //  .. 14778368
  unsigned* pc1 = (unsigned*)(ws + 14778368);              //  .. 18972672
  int* ids      = (int*)(ws + 18972672);                   //  .. 19038208
  int* fulll    = (int*)(ws + 19038208);                   //  .. 19103744
  unsigned* items = (unsigned*)(ws + 19103744);            //  .. 20152320
  unsigned* wnmax  = (unsigned*)(ws + 20152320);           // ctrl 16 B
  unsigned* icount = (unsigned*)(ws + 20152324);
  unsigned* fcount = (unsigned*)(ws + 20152328);
  float* counts = (float*)(ws + 20152336);                 //  .. 20185104
  float* sums   = (float*)(ws + 20185104);                 //  .. 24379408
  unsigned long long* keys = (unsigned long long*)(ws + 24379408); // .. 24510480
  (void)in_sizes; (void)n_in; (void)out_size; (void)ws_size;

  // zero ctrl+counts+sums, then 0xFF keys (keys sentinel = ~0ull)
  hipMemsetAsync(ws + 20152320, 0, 16 + 32768 + 4194304, stream);
  hipMemsetAsync(ws + 24379408, 0xFF, N_ROWS * 8, stream);

  prep_x<<<256, 256, 0, stream>>>(enc, Ap, xnorm);
  prep_w<<<K_CODES / 64, 256, 0, stream>>>(w, Bp, wnorm, wnmax);
  gemm_argmin<<<dim3(K_CODES / 128, N_ROWS / 128), 256, 0, stream>>>(
      Ap, Bp, xnorm, wnorm, pd1, pc1, pd2);
  merge_classify<<<N_ROWS / 256, 256, 0, stream>>>(
      pd1, pc1, pd2, xnorm, wnmax, ids, items, icount, fulll, fcount, out_ids);
  refine_items<<<256, 256, 0, stream>>>(enc, w, wnorm, items, icount, keys);
  resolve_keys<<<N_ROWS / 256, 256, 0, stream>>>(keys, ids, out_ids);
  refine_full<<<512, 256, 0, stream>>>(enc, w, wnorm, fulll, fcount, ids, out_ids);
  scatter_counts<<<N_ROWS / 256, 256, 0, stream>>>(ids, counts);
  scatter_sums<<<(N_ROWS * C_DIM) / 256, 256, 0, stream>>>(enc, ids, sums);
  finalize_w<<<(K_CODES * C_DIM) / 256, 256, 0, stream>>>(w, sums, counts, out_w);
  write_q<<<(N_ROWS * C_DIM) / 256, 256, 0, stream>>>(enc, w, ids, out_q);
}

// Round 6
// 441.042 us; speedup vs baseline: 1.9685x; 1.2529x over previous
//
#include <hip/hip_runtime.h>
#include <stdint.h>
#include <stddef.h>

// ---------------------------------------------------------------------------
// VQ-VAE quantizer, MI355X.  dist(n,k) = ||x||^2 + ||w_k||^2 - 2 x.w_k.
// f16 GEMM (KD=128), fragment-linear A/B, no LDS/barriers in K-loop.
// Refine architecture (R4, proven): per-row threshold T = d1~ + 2E.
//   - every colblock with top1~ <= T contributes its top-1 code as candidate
//   - if any colblock's top2~ <= T -> exact full rescan for the row
//   - candidates resolved by exact fp32 distance + u64 atomicMin key
// R6: refine_full sliced across the codebook (8 slices x 1024 codes); each
//     (row,slice) is one block -> no straggler blocks.  Per-(row,code)
//     arithmetic order bit-identical to R4/R5.  Results merge into the same
//     keys[] array refine_items uses (disjoint row sets), resolved after.
// ---------------------------------------------------------------------------

#define N_ROWS   16384      // B*H*W = 16*32*32
#define K_CODES  8192
#define C_DIM    128

typedef _Float16 f16x8 __attribute__((ext_vector_type(8)));
typedef float    f32x4 __attribute__((ext_vector_type(4)));

// ---------------- prep: pack encodings -> Ap fragment-linear, xnorm --------
// Ap layout: half Ap[rowtile R=n>>4][kchunk C=c>>5][lane][8]
//   lane = (n&15) + 16*((c&31)>>3), elem j = c&7   (MFMA A-operand order)
__global__ __launch_bounds__(256) void prep_x(const float* __restrict__ enc,
                                              _Float16* __restrict__ Ap,
                                              float* __restrict__ xnorm) {
  __shared__ float t[128][65];
  const int tid = threadIdx.x;
  const int b = blockIdx.x >> 4;
  const int hw0 = (blockIdx.x & 15) << 6;
  #pragma unroll
  for (int i = 0; i < 32; ++i) {
    int idx = i * 256 + tid;
    int c = idx >> 6, hwl = idx & 63;
    t[c][hwl] = enc[((size_t)(b * 128 + c) << 10) + hw0 + hwl];
  }
  __syncthreads();
  const int r = tid >> 2, sub = tid & 3;         // row-in-block, k-chunk
  const int n = (b << 10) + hw0 + r;
  const int R = n >> 4, m = n & 15;
  float s = 0.f;
  #pragma unroll
  for (int q = 0; q < 4; ++q) {
    f16x8 hv;
    #pragma unroll
    for (int e = 0; e < 8; ++e) {
      float v = t[sub * 32 + q * 8 + e][r];
      s += v * v;
      hv[e] = (_Float16)v;
    }
    *(f16x8*)(Ap + ((size_t)(R * 4 + sub) * 64 + (m + 16 * q)) * 8) = hv;
  }
  s += __shfl_xor(s, 1);
  s += __shfl_xor(s, 2);
  if (sub == 0) xnorm[n] = s;
}

// ---------------- prep: pack weight -> Bp fragment-linear, wnorm, wnmax ----
__global__ __launch_bounds__(256) void prep_w(const float* __restrict__ w,
                                              _Float16* __restrict__ Bp,
                                              float* __restrict__ wnorm,
                                              unsigned* __restrict__ wnmax) {
  const int tid = threadIdx.x;
  const int kk = blockIdx.x * 64 + (tid >> 2), sub = tid & 3;
  const int R = kk >> 4, m = kk & 15;
  const float* base = w + (size_t)kk * C_DIM + sub * 32;
  float s = 0.f;
  #pragma unroll
  for (int q = 0; q < 4; ++q) {
    f16x8 hv;
    float4 va = *(const float4*)(base + q * 8);
    float4 vb = *(const float4*)(base + q * 8 + 4);
    float vv[8] = {va.x, va.y, va.z, va.w, vb.x, vb.y, vb.z, vb.w};
    #pragma unroll
    for (int e = 0; e < 8; ++e) { s += vv[e] * vv[e]; hv[e] = (_Float16)vv[e]; }
    *(f16x8*)(Bp + ((size_t)(R * 4 + sub) * 64 + (m + 16 * q)) * 8) = hv;
  }
  s += __shfl_xor(s, 1);
  s += __shfl_xor(s, 2);
  if (sub == 0) {
    wnorm[kk] = s;
    atomicMax(wnmax, __float_as_uint(s));        // s > 0 -> bit-monotone
  }
}

// ---------------- main GEMM + fused per-(row,colblock) top-2 ---------------
// 128x128 tile, 4 waves 2x2, wave tile 64x64 = 4x4 MFMA f32_16x16x32_f16.
// Fragments loaded straight from global (L1/L2); no LDS, no main-loop barrier.
__global__ __launch_bounds__(256, 4) void gemm_argmin(
    const _Float16* __restrict__ Ap, const _Float16* __restrict__ Bp,
    const float* __restrict__ xnorm, const float* __restrict__ wnorm,
    float* __restrict__ pd1, unsigned* __restrict__ pc1,
    float* __restrict__ pd2)
{
  __shared__ float    e_d1[256], e_d2[256];
  __shared__ unsigned e_c1[256];
  const int tid = threadIdx.x;
  const int lane = tid & 63, wave = tid >> 6;
  const int wr = wave >> 1, wc = wave & 1;
  const int m = lane & 15, q = lane >> 4;
  const int row0 = blockIdx.y * 128, col0 = blockIdx.x * 128;
  const int Tr0 = blockIdx.y * 8 + wr * 4;       // A row-tiles (16 rows each)
  const int Tc0 = blockIdx.x * 8 + wc * 4;       // B code-tiles

  f32x4 acc[4][4];
  #pragma unroll
  for (int i = 0; i < 4; ++i)
    #pragma unroll
    for (int j = 0; j < 4; ++j) acc[i][j] = (f32x4){0.f, 0.f, 0.f, 0.f};

  #pragma unroll
  for (int kc = 0; kc < 4; ++kc) {
    f16x8 a[4], b[4];
    #pragma unroll
    for (int ti = 0; ti < 4; ++ti)
      a[ti] = *(const f16x8*)(Ap + (((size_t)(Tr0 + ti) * 4 + kc) << 9) + (lane << 3));
    #pragma unroll
    for (int tj = 0; tj < 4; ++tj)
      b[tj] = *(const f16x8*)(Bp + (((size_t)(Tc0 + tj) * 4 + kc) << 9) + (lane << 3));
    #pragma unroll
    for (int ti = 0; ti < 4; ++ti)
      #pragma unroll
      for (int tj = 0; tj < 4; ++tj)
        acc[ti][tj] = __builtin_amdgcn_mfma_f32_16x16x32_f16(
            a[ti], b[tj], acc[ti][tj], 0, 0, 0);
  }

  // ---- epilogue: dist + per-row top2; C/D layout col=lane&15, row=4q+r ----
  float wn[4];
  #pragma unroll
  for (int tj = 0; tj < 4; ++tj) wn[tj] = wnorm[col0 + wc * 64 + tj * 16 + m];

  #pragma unroll
  for (int ti = 0; ti < 4; ++ti) {
    #pragma unroll
    for (int r_ = 0; r_ < 4; ++r_) {
      int row_l = wr * 64 + ti * 16 + 4 * q + r_;
      float xn = xnorm[row0 + row_l];
      float d1 = __builtin_inff(), d2 = __builtin_inff();
      unsigned c1 = 0;
      #pragma unroll
      for (int tj = 0; tj < 4; ++tj) {           // ascending col; tie -> lower
        float dd = (xn + wn[tj]) - 2.0f * acc[ti][tj][r_];
        unsigned cc = (unsigned)(col0 + wc * 64 + tj * 16 + m);
        if (dd < d1) { d2 = d1; d1 = dd; c1 = cc; }
        else         { d2 = fminf(d2, dd); }
      }
      #pragma unroll
      for (int s = 1; s <= 8; s <<= 1) {         // 16-lane butterfly over m
        float    od1 = __shfl_xor(d1, s), od2 = __shfl_xor(d2, s);
        unsigned oc1 = (unsigned)__shfl_xor((int)c1, s);
        float nd2 = fminf(fminf(d2, od2), fmaxf(d1, od1));
        if (od1 < d1 || (od1 == d1 && oc1 < c1)) { d1 = od1; c1 = oc1; }
        d2 = nd2;
      }
      if (m == 0) {
        int ei = wc * 128 + row_l;
        e_d1[ei] = d1; e_c1[ei] = c1; e_d2[ei] = d2;
      }
    }
  }
  __syncthreads();
  if (tid < 128) {                               // merge the 2 col-halves
    float d1 = e_d1[tid], d2 = e_d2[tid];
    unsigned c1 = e_c1[tid];
    float od1 = e_d1[128 + tid], od2 = e_d2[128 + tid];
    unsigned oc1 = e_c1[128 + tid];
    float nd2 = fminf(fminf(d2, od2), fmaxf(d1, od1));
    if (od1 < d1 || (od1 == d1 && oc1 < c1)) { d1 = od1; c1 = oc1; }
    d2 = nd2;
    size_t pi = (size_t)blockIdx.x * N_ROWS + (size_t)(row0 + tid);
    pd1[pi] = d1; pc1[pi] = c1; pd2[pi] = d2;
  }
}

// ---------------- classify: threshold-collect over 64 colblocks ------------
__global__ void merge_classify(const float* __restrict__ pd1,
                               const unsigned* __restrict__ pc1,
                               const float* __restrict__ pd2,
                               const float* __restrict__ xnorm,
                               const unsigned* __restrict__ wnmax,
                               int* __restrict__ ids,
                               unsigned* __restrict__ items,
                               unsigned* __restrict__ icount,
                               int* __restrict__ fulll,
                               unsigned* __restrict__ fcount,
                               float* __restrict__ out_ids) {
  int row = blockIdx.x * 256 + threadIdx.x;
  // pass 1: global top-1, 4 independent sub-chains (ILP), lex-combine.
  float da = __builtin_inff(), db = __builtin_inff(),
        dc = __builtin_inff(), dd = __builtin_inff();
  unsigned ca = 0, cb_ = 0, cc = 0, cd = 0;
  for (int cb = 0; cb < 64; cb += 4) {
    size_t i0 = (size_t)cb * N_ROWS + row;
    float va = pd1[i0], vb = pd1[i0 + (size_t)N_ROWS],
          vc = pd1[i0 + 2 * (size_t)N_ROWS], vd = pd1[i0 + 3 * (size_t)N_ROWS];
    unsigned ka = pc1[i0], kb = pc1[i0 + (size_t)N_ROWS],
             kc = pc1[i0 + 2 * (size_t)N_ROWS], kd = pc1[i0 + 3 * (size_t)N_ROWS];
    if (va < da || (va == da && ka < ca)) { da = va; ca = ka; }
    if (vb < db || (vb == db && kb < cb_)) { db = vb; cb_ = kb; }
    if (vc < dc || (vc == dc && kc < cc)) { dc = vc; cc = kc; }
    if (vd < dd || (vd == dd && kd < cd)) { dd = vd; cd = kd; }
  }
  float d1 = da; unsigned c1 = ca;
  if (db < d1 || (db == d1 && cb_ < c1)) { d1 = db; c1 = cb_; }
  if (dc < d1 || (dc == d1 && cc < c1)) { d1 = dc; c1 = cc; }
  if (dd < d1 || (dd == d1 && cd < c1)) { d1 = dd; c1 = cd; }

  float wm = __uint_as_float(*wnmax);
  float twoE = 2.0f * (0.0029297f * sqrtf(xnorm[row] * wm) + 2e-4f);
  float T = d1 + twoE;
  // pass 2: collect candidate codes / full-rescan flag (order-independent)
  bool full = false;
  int nc = 0;
  unsigned cands[6];
  #pragma unroll 4
  for (int cb = 0; cb < 64; ++cb) {
    size_t i = (size_t)cb * N_ROWS + row;
    if (pd2[i] <= T) { full = true; }
    else if (pd1[i] <= T) {
      if (nc < 6) cands[nc++] = pc1[i];
      else full = true;
    }
  }
  ids[row] = (int)c1;                            // provisional (exact if nc==1 && !full)
  out_ids[row] = (float)c1;
  if (full) {
    unsigned fi = atomicAdd(fcount, 1u);
    fulll[fi] = row;
  } else if (nc >= 2) {
    unsigned base = atomicAdd(icount, (unsigned)nc);
    for (int i = 0; i < nc; ++i)
      items[base + i] = ((unsigned)row << 13) | cands[i];
  }
}

// ---------------- exact fp32 per-candidate compare (atomicMin key) ---------
__global__ void refine_items(const float* __restrict__ enc,
                             const float* __restrict__ w,
                             const float* __restrict__ wnorm,
                             const unsigned* __restrict__ items,
                             const unsigned* __restrict__ icount,
                             unsigned long long* __restrict__ keys) {
  const unsigned cnt = *icount;
  for (unsigned i = blockIdx.x * blockDim.x + threadIdx.x; i < cnt;
       i += gridDim.x * blockDim.x) {
    unsigned it = items[i];
    int row = (int)(it >> 13), c = (int)(it & 8191u);
    int b = row >> 10, hw = row & 1023;
    const float* xb = enc + ((size_t)b << 17) + hw;
    const float* wk = w + (size_t)c * C_DIM;
    float xn = 0.f, s = 0.f;
    for (int cc = 0; cc < C_DIM; ++cc) {
      float x = xb[(size_t)cc << 10];
      xn += x * x;
      s = fmaf(x, wk[cc], s);
    }
    float d = (xn + wnorm[c]) - 2.0f * s;
    unsigned sb = __float_as_uint(d);
    sb = (sb >> 31) ? ~sb : (sb | 0x80000000u);  // sortable float bits
    unsigned long long key = ((unsigned long long)sb << 32) | (unsigned)c;
    atomicMin(&keys[row], key);                  // tie -> lowest code
  }
}

// ---------------- exact fp32 full rescan, sliced over the codebook ---------
// Work item = (flagged row, 1024-code slice); 8 slices cover the codebook.
// 256 threads x 4 codes each; per-(row,code) fmaf chain order bit-identical
// to R4/R5.  Row results merge via atomicMin into keys[] (sortable-float
// packing, same as refine_items; full-rows and item-rows are disjoint).
__global__ __launch_bounds__(256) void refine_full(
    const float* __restrict__ enc, const float* __restrict__ w,
    const float* __restrict__ wnorm,
    const int* __restrict__ fulll, const unsigned* __restrict__ fcount,
    unsigned long long* __restrict__ keys) {
  __shared__ __align__(16) float xs[128];
  __shared__ unsigned long long red[4];
  const int tid = threadIdx.x;
  const int lane = tid & 63, wave = tid >> 6;
  const unsigned cnt = *fcount;
  const unsigned nitems = cnt * 8;
  for (unsigned item = blockIdx.x; item < nitems; item += gridDim.x) {
    const int row = fulll[item >> 3];
    const int slice = (int)(item & 7u);
    if (tid < 128)                               // stage x row
      xs[tid] = enc[(((size_t)(row >> 10) * 128 + tid) << 10) + (row & 1023)];
    __syncthreads();
    float xn = 0.f;                              // serial order (R4-identical)
    for (int c = 0; c < 128; ++c) xn += xs[c] * xs[c];
    const int k0 = slice * 1024 + tid * 4;
    float S[4];
    #pragma unroll
    for (int j = 0; j < 4; ++j) S[j] = 0.f;
    for (int c4 = 0; c4 < 32; ++c4) {
      float4 xv = *(const float4*)(&xs[c4 * 4]);
      #pragma unroll
      for (int j = 0; j < 4; ++j) {
        float4 wv = *(const float4*)(w + (size_t)(k0 + j) * C_DIM + c4 * 4);
        S[j] = fmaf(xv.x, wv.x, S[j]);
        S[j] = fmaf(xv.y, wv.y, S[j]);
        S[j] = fmaf(xv.z, wv.z, S[j]);
        S[j] = fmaf(xv.w, wv.w, S[j]);
      }
    }
    unsigned long long best = ~0ull;
    #pragma unroll
    for (int j = 0; j < 4; ++j) {
      float d = (xn + wnorm[k0 + j]) - 2.0f * S[j];
      unsigned sb = __float_as_uint(d);
      sb = (sb >> 31) ? ~sb : (sb | 0x80000000u);
      unsigned long long key = ((unsigned long long)sb << 32) | (unsigned)(k0 + j);
      best = best < key ? best : key;
    }
    #pragma unroll
    for (int s = 1; s <= 32; s <<= 1) {          // 64-lane u64 butterfly
      unsigned long long ok = __shfl_xor(best, s);
      best = ok < best ? ok : best;
    }
    if (lane == 0) red[wave] = best;
    __syncthreads();
    if (tid == 0) {
      unsigned long long bk = red[0];
      #pragma unroll
      for (int wv = 1; wv < 4; ++wv) bk = red[wv] < bk ? red[wv] : bk;
      atomicMin(&keys[row], bk);
    }
    __syncthreads();                             // xs reused next item
  }
}

// ---------------- resolve refined rows from keys ---------------------------
__global__ void resolve_keys(const unsigned long long* __restrict__ keys,
                             int* __restrict__ ids, float* __restrict__ out_ids) {
  int row = blockIdx.x * 256 + threadIdx.x;
  unsigned long long k = keys[row];
  if (k != ~0ull) {
    int c = (int)(unsigned)(k & 0xffffffffu);
    ids[row] = c;
    out_ids[row] = (float)c;
  }
}

// ---------------- scatter stats --------------------------------------------
__global__ void scatter_counts(const int* __restrict__ ids, float* counts) {
  int n = blockIdx.x * 256 + threadIdx.x;
  unsafeAtomicAdd(&counts[ids[n]], 1.0f);
}
__global__ void scatter_sums(const float* __restrict__ enc,
                             const int* __restrict__ ids, float* sums) {
  int e = blockIdx.x * 256 + threadIdx.x;        // linear over enc [B,C,H,W]
  int c = (e >> 10) & 127;
  int b = e >> 17;
  int n = (b << 10) | (e & 1023);
  unsafeAtomicAdd(&sums[(size_t)ids[n] * C_DIM + c], enc[e]);
}

// ---------------- finalize: EMA weight + straight-through q ----------------
__global__ void finalize_w(const float* __restrict__ w,
                           const float* __restrict__ sums,
                           const float* __restrict__ counts,
                           float* __restrict__ outw) {
  int i = blockIdx.x * 256 + threadIdx.x;
  int k = i >> 7;
  const float omd = (float)(1.0 - 0.99);
  float mean = sums[i] / (counts[k] + 1e-12f);
  outw[i] = 0.99f * w[i] + omd * mean;
}
__global__ void write_q(const float* __restrict__ enc,
                        const float* __restrict__ w,
                        const int* __restrict__ ids, float* __restrict__ outq) {
  int e = blockIdx.x * 256 + threadIdx.x;
  int c = (e >> 10) & 127;
  int b = e >> 17;
  int n = (b << 10) | (e & 1023);
  float x = enc[e];
  float wq = w[(size_t)ids[n] * C_DIM + c];
  outq[e] = x + (wq - x);
}

// ---------------------------------------------------------------------------
extern "C" void kernel_launch(void* const* d_in, const int* in_sizes, int n_in,
                              void* d_out, int out_size, void* d_ws, size_t ws_size,
                              hipStream_t stream) {
  const float* enc = (const float*)d_in[0];      // [16,128,32,32]
  const float* w   = (const float*)d_in[1];      // [8192,128]
  float* out = (float*)d_out;
  float* out_ids = out;                          // 16384 (ids as float)
  float* out_q   = out + N_ROWS;                 // 2097152
  float* out_w   = out + N_ROWS + N_ROWS * C_DIM;// 1048576

  char* ws = (char*)d_ws;
  _Float16* Ap  = (_Float16*)(ws);                         //  0 .. 4194304
  _Float16* Bp  = (_Float16*)(ws + 4194304);               //  .. 6291456
  float* xnorm  = (float*)(ws + 6291456);                  //  .. 6356992
  float* wnorm  = (float*)(ws + 6356992);                  //  .. 6389760
  float* pd1    = (float*)(ws + 6389760);                  //  .. 10584064
  float* pd2    = (float*)(ws + 10584064);                 //  .. 14778368
  unsigned* pc1 = (unsigned*)(ws + 14778368);              //  .. 18972672
  int* ids      = (int*)(ws + 18972672);                   //  .. 19038208
  int* fulll    = (int*)(ws + 19038208);                   //  .. 19103744
  unsigned* items = (unsigned*)(ws + 19103744);            //  .. 20152320
  unsigned* wnmax  = (unsigned*)(ws + 20152320);           // ctrl 16 B
  unsigned* icount = (unsigned*)(ws + 20152324);
  unsigned* fcount = (unsigned*)(ws + 20152328);
  float* counts = (float*)(ws + 20152336);                 //  .. 20185104
  float* sums   = (float*)(ws + 20185104);                 //  .. 24379408
  unsigned long long* keys = (unsigned long long*)(ws + 24379408); // .. 24510480
  (void)in_sizes; (void)n_in; (void)out_size; (void)ws_size;

  // zero ctrl+counts+sums, then 0xFF keys (keys sentinel = ~0ull)
  hipMemsetAsync(ws + 20152320, 0, 16 + 32768 + 4194304, stream);
  hipMemsetAsync(ws + 24379408, 0xFF, N_ROWS * 8, stream);

  prep_x<<<256, 256, 0, stream>>>(enc, Ap, xnorm);
  prep_w<<<K_CODES / 64, 256, 0, stream>>>(w, Bp, wnorm, wnmax);
  gemm_argmin<<<dim3(K_CODES / 128, N_ROWS / 128), 256, 0, stream>>>(
      Ap, Bp, xnorm, wnorm, pd1, pc1, pd2);
  merge_classify<<<N_ROWS / 256, 256, 0, stream>>>(
      pd1, pc1, pd2, xnorm, wnmax, ids, items, icount, fulll, fcount, out_ids);
  refine_items<<<256, 256, 0, stream>>>(enc, w, wnorm, items, icount, keys);
  refine_full<<<2048, 256, 0, stream>>>(enc, w, wnorm, fulll, fcount, keys);
  resolve_keys<<<N_ROWS / 256, 256, 0, stream>>>(keys, ids, out_ids);
  scatter_counts<<<N_ROWS / 256, 256, 0, stream>>>(ids, counts);
  scatter_sums<<<(N_ROWS * C_DIM) / 256, 256, 0, stream>>>(enc, ids, sums);
  finalize_w<<<(K_CODES * C_DIM) / 256, 256, 0, stream>>>(w, sums, counts, out_w);
  write_q<<<(N_ROWS * C_DIM) / 256, 256, 0, stream>>>(enc, w, ids, out_q);
}